// Round 19
// baseline (56.884 us; speedup 1.0000x reference)
//
#include <hip/hip_runtime.h>
#include <math.h>

typedef unsigned int u32;
typedef unsigned long long u64;

constexpr int N_IMG = 16;
constexpr int C_CLS = 80;
constexpr int H_DIM = 160;
constexpr int W_DIM = 160;
constexpr int L_LOC = H_DIM * W_DIM;   // 25600
constexpr int LC    = L_LOC * C_CLS;   // 2048000
constexpr int K_TOP = 1000;
constexpr int NB    = 1024;            // histogram buckets: (bits-KEY_BASE)>>16
constexpr int CAP   = 2048;            // candidate cap per image (16KB LDS)
constexpr int GBUF  = 1024;            // per-segment survivor buffer (u64)
constexpr int HPAIR = 256;             // per-segment (bucket,count) pair cap
constexpr int CHUNK_L = 320;           // locations per megaA block (r12-proven)
constexpr int NSEG  = L_LOC / CHUNK_L; // 80 segments per image
constexpr int CF4   = CHUNK_L / 4;     // 80 float4 per class row
constexpr int SPAN  = 80;              // max buckets above B_SAFE (1024-948=76)
constexpr float THRESH = 0.05f;
constexpr u32 KEY_BASE = 119u << 23;   // 0x3B800000
constexpr float T0     = 0.7f;
constexpr float DELTA  = 0.05f;        // conservative slack in logit space
// buckets >= B_SAFE have lower bound > 0.7f, where spec is provably a superset
constexpr int B_SAFE  = ((0x3F340000u - KEY_BASE) >> 16);  // 948

// ---- workspace layout (bytes); NOTHING needs pre-zeroing ----
constexpr size_t WS_BCNT  = 0;                                   // u32[16*80]
constexpr size_t WS_HCNT  = 8192;                                // u32[16*80]
constexpr size_t WS_HPAIR = 16384;                               // u64[16*80*256] = 2.5MB
constexpr size_t WS_SPEC  = WS_HPAIR + (size_t)N_IMG * NSEG * HPAIR * 8;  // 10MB

__device__ inline float sigmoidf_acc(float x) { return 1.0f / (1.0f + expf(-x)); }

__device__ inline u32 score_bucket(u32 bits) {
    u32 b = (bits >= KEY_BASE) ? ((bits - KEY_BASE) >> 16) : 0u;
    return b > (u32)(NB - 1) ? (u32)(NB - 1) : b;
}

// bitonic sort (slow path only)
__device__ inline void bitonic_desc(u64* sk, u32 M, int tid, int nthr) {
    u32 n2 = 1024; while (n2 < M) n2 <<= 1;
    for (u32 i = tid; i < n2; i += nthr) if (i >= M) sk[i] = 0ull;
    __syncthreads();
    for (u32 k = 2; k <= n2; k <<= 1) {
        for (u32 j = k >> 1; j > 0; j >>= 1) {
            for (u32 i = tid; i < n2; i += nthr) {
                u32 ixj = i ^ j;
                if (ixj > i) {
                    u64 a = sk[i], b = sk[ixj];
                    bool front = ((i & k) == 0);
                    if (front ? (a < b) : (a > b)) { sk[i] = b; sk[ixj] = a; }
                }
            }
            __syncthreads();
        }
    }
}

// decode one candidate key and write its output row at rank k
__device__ inline void emit_one(int n, u64 kk, int k,
                                const float* locations, const float* breg,
                                const int* isz, float* out) {
    float* ob = out;                                  // boxes  [N,K,4]
    float* os = out + (size_t)N_IMG * K_TOP * 4;      // scores [N,K]
    float* ol = os + (size_t)N_IMG * K_TOP;           // labels [N,K]
    float* ov = ol + (size_t)N_IMG * K_TOP;           // valid  [N,K]
    const float wimg = (float)isz[n * 2 + 1];
    const float himg = (float)isz[n * 2 + 0];
    const float* rn = breg + (size_t)n * 4 * L_LOC;
    size_t slot = (size_t)n * K_TOP + k;
    u32 vb = (u32)(kk >> 32);
    u32 idx = ~(u32)(kk & 0xFFFFFFFFull);
    float val = __uint_as_float(vb);
    int loc = (int)(idx / (u32)C_CLS);
    int c = (int)(idx - (u32)loc * (u32)C_CLS);
    float lx = locations[loc * 2 + 0], ly = locations[loc * 2 + 1];
    float r0 = rn[0 * L_LOC + loc], r1 = rn[1 * L_LOC + loc];
    float r2 = rn[2 * L_LOC + loc], r3 = rn[3 * L_LOC + loc];
    float x1 = lx - r0, y1 = ly - r1, x2 = lx + r2, y2 = ly + r3;
    x1 = fminf(fmaxf(x1, 0.0f), wimg - 1.0f);
    y1 = fminf(fmaxf(y1, 0.0f), himg - 1.0f);
    x2 = fminf(fmaxf(x2, 0.0f), wimg - 1.0f);
    y2 = fminf(fmaxf(y2, 0.0f), himg - 1.0f);
    float wsz = x2 - x1 + 1.0f, hsz = y2 - y1 + 1.0f;
    bool v = (val > 0.0f) && (wsz >= 0.0f) && (hsz >= 0.0f);  // MIN_SIZE = 0
    float vf = v ? 1.0f : 0.0f;
    ob[slot * 4 + 0] = x1 * vf;
    ob[slot * 4 + 1] = y1 * vf;
    ob[slot * 4 + 2] = x2 * vf;
    ob[slot * 4 + 3] = y2 * vf;
    os[slot] = v ? sqrtf(fmaxf(val, 0.0f)) : 0.0f;
    ol[slot] = (float)(c + 1);
    ov[slot] = vf;
}

// decode + write K rows from a sorted array (slow path)
__device__ inline void emit_rows(int n, const u64* sk, u32 cand_slots, const u32* fill,
                                 const float* locations, const float* breg,
                                 const int* isz, float* out, int tid, int nthr) {
    float* ob = out;
    float* os = out + (size_t)N_IMG * K_TOP * 4;
    float* ol = os + (size_t)N_IMG * K_TOP;
    float* ov = ol + (size_t)N_IMG * K_TOP;
    for (int k = tid; k < K_TOP; k += nthr) {
        size_t slot = (size_t)n * K_TOP + k;
        if ((u32)k < cand_slots) {
            emit_one(n, sk[k], k, locations, breg, isz, out);
        } else {
            u32 fi = fill ? fill[k - (int)cand_slots] : 0u;
            ob[slot * 4 + 0] = 0.0f; ob[slot * 4 + 1] = 0.0f;
            ob[slot * 4 + 2] = 0.0f; ob[slot * 4 + 3] = 0.0f;
            os[slot] = 0.0f;
            ol[slot] = (float)((int)(fi % (u32)C_CLS) + 1);
            ov[slot] = 0.0f;
        }
    }
}

// --- kernel 1 (hot pass): r15 stream + survivor scoring; hist exported as
//     compact (bucket,count) pairs to a PRIVATE region (no global atomics,
//     no pre-zeroed state anywhere) ---
__global__ __launch_bounds__(256) void megaA_kernel(
        const float* __restrict__ cls, const float* __restrict__ ctr,
        u64* __restrict__ spec, u32* __restrict__ bcnt,
        u32* __restrict__ hcnt, u64* __restrict__ hpairs) {
    __shared__ __align__(16) float xm[CHUNK_L];
    __shared__ float sct[CHUNK_L];
    __shared__ u64 sbuf[GBUF];
    __shared__ u32 lh[NB];
    __shared__ u32 lcnt, lof, hcl;
    const int tid = threadIdx.x;
    const u32 n = blockIdx.y;
    const u32 lbase = blockIdx.x * (u32)CHUNK_L;
    for (int b = tid; b < NB; b += 256) lh[b] = 0u;
    if (tid == 0) { lcnt = 0; lof = 0; hcl = 0; }
    // prologue: per-location sigmoid(ctr) and logit threshold
    for (int i = tid; i < CHUNK_L; i += 256) {
        float s = sigmoidf_acc(ctr[(size_t)n * L_LOC + lbase + i]);
        sct[i] = s;
        float t = T0 / s;                   // need sigmoid(x) >= t for score >= T0
        xm[i] = (t >= 1.0f) ? 3.0e38f : (logf(t / (1.0f - t)) - DELTA);
    }
    __syncthreads();
    const float* base = cls + (size_t)n * LC + lbase;
    u32 m0 = 0u, m1 = 0u, m2 = 0u, m3 = 0u;
#pragma unroll
    for (int g = 0; g < 5; ++g) {
        float4 v[5]; u32 l4a[5];
#pragma unroll
        for (int k = 0; k < 5; ++k) {
            int q = g * 5 + k;
            u32 f = (u32)q * 256u + (u32)tid;        // f4 index in [0, 6400)
            u32 c = f / (u32)CF4;
            u32 l4 = f - c * (u32)CF4;
            l4a[k] = l4;
            v[k] = *reinterpret_cast<const float4*>(base + (size_t)c * L_LOC + l4 * 4u);
        }
#pragma unroll
        for (int k = 0; k < 5; ++k) {
            int q = g * 5 + k;
            float4 m4 = *reinterpret_cast<const float4*>(&xm[l4a[k] * 4u]);
            u32 nib = (v[k].x >= m4.x ? 1u : 0u) | (v[k].y >= m4.y ? 2u : 0u)
                    | (v[k].z >= m4.z ? 4u : 0u) | (v[k].w >= m4.w ? 8u : 0u);
            u32 sh = (u32)(q & 7) * 4u;
            if ((q >> 3) == 0) m0 |= nib << sh;
            else if ((q >> 3) == 1) m1 |= nib << sh;
            else if ((q >> 3) == 2) m2 |= nib << sh;
            else m3 |= nib << sh;
        }
    }
    // survivor phase (decoupled from the stream): exact score + LDS hist + append
    u32 words[4] = {m0, m1, m2, m3};
#pragma unroll
    for (int w = 0; w < 4; ++w) {
        u32 bits = words[w];
        while (bits) {
            u32 b = (u32)__ffs(bits) - 1u; bits &= bits - 1u;
            u32 q = (u32)w * 8u + (b >> 2), j = b & 3u;
            u32 f = q * 256u + (u32)tid;
            u32 c = f / (u32)CF4;
            u32 l4 = f - c * (u32)CF4;
            u32 li = l4 * 4u + j, loc = lbase + li;
            float x = base[(size_t)c * L_LOC + li];  // L3-resident re-read
            float s = sigmoidf_acc(x);               // exact reference formula
            float scr = s * sct[li];
            u32 sb = __float_as_uint(scr);
            atomicAdd(&lh[score_bucket(sb)], 1u);
            u32 p = atomicAdd(&lcnt, 1u);
            if (p < (u32)GBUF)
                sbuf[p] = ((u64)sb << 32) | (u32)(~(loc * (u32)C_CLS + c));
            else lof = 1u;
        }
    }
    __syncthreads();
    // compact non-zero hist buckets into private (bucket,count) pairs
    u64* hp = hpairs + ((size_t)n * NSEG + blockIdx.x) * HPAIR;
    for (int b = tid; b < NB; b += 256) {
        u32 v = lh[b];
        if (v) {
            u32 p = atomicAdd(&hcl, 1u);
            if (p < (u32)HPAIR) hp[p] = ((u64)(u32)b << 32) | v;
            else lof = 1u;
        }
    }
    __syncthreads();
    const u32 m_ = lcnt > (u32)GBUF ? (u32)GBUF : lcnt;
    u64* sp = spec + ((size_t)n * NSEG + blockIdx.x) * GBUF;
    for (u32 i = tid; i < m_; i += 256) sp[i] = sbuf[i];
    if (tid == 0) {
        u32 hc = hcl > (u32)HPAIR ? (u32)HPAIR : hcl;
        hcnt[n * NSEG + blockIdx.x] = hc;
        bcnt[n * NSEG + blockIdx.x] =
            m_ | ((lof || lcnt > (u32)GBUF || hcl > (u32)HPAIR) ? 0x80000000u : 0u);
    }
}

// --- kernel 2: FAST finish: pair-scatter hist -> suffix-scan -> wave-per-segment
//     filter with bucket placement -> within-bucket rank -> direct emit (NO SORT).
//     Inlined SLOW fallback (full rescan; never taken in practice). ---
__global__ __launch_bounds__(1024) void finishC_kernel(
        const u64* __restrict__ hpairs, const u32* __restrict__ hcnt,
        const u64* __restrict__ spec, const u32* __restrict__ bcnt,
        const float* __restrict__ cls, const float* __restrict__ ctr,
        const float* __restrict__ locations, const float* __restrict__ breg,
        const int* __restrict__ isz, float* __restrict__ out) {
    __shared__ u32 lh[NB];                 // raw hist -> (destructive) suffix sums
    __shared__ u64 sk[CAP];
    __shared__ u32 fill[K_TOP];
    __shared__ u32 segc[NSEG];
    __shared__ u32 hcl[NSEG];
    __shared__ u32 sfxl[SPAN + 1];
    __shared__ u32 bkc[SPAN];
    __shared__ u32 s_b, s_cnt, s_lcnt, s_filled, s_bad;
    const int n = blockIdx.x;
    const int tid = threadIdx.x;
    const int wid = tid >> 6, lane = tid & 63;       // 16 waves of 64
    if (tid == 0) { s_b = 0xFFFFFFFFu; s_lcnt = 0; s_cnt = 0; s_filled = 0; s_bad = 0; }
    lh[tid] = 0u;
    __syncthreads();
    if (tid < NSEG) {
        u32 v = bcnt[n * NSEG + tid];
        segc[tid] = v & 0x7FFFFFFFu;
        hcl[tid] = hcnt[n * NSEG + tid];
        if (v & 0x80000000u) atomicOr(&s_bad, 1u);
    }
    __syncthreads();
    // rebuild hist from compact pairs: one WAVE per segment, 16 concurrent
    const u64* hpn = hpairs + (size_t)n * NSEG * HPAIR;
    for (int sr = 0; sr < NSEG; sr += 16) {
        int s2 = sr + wid;                            // NSEG % 16 == 0
        u32 hc = hcl[s2];
        const u64* hp = hpn + (size_t)s2 * HPAIR;
        for (u32 i = lane; i < hc; i += 64) {
            u64 pr = hp[i];
            atomicAdd(&lh[(u32)(pr >> 32)], (u32)pr);
        }
    }
    __syncthreads();
    // suffix sums: lh[b] = count with bucket >= b (r12-proven)
    for (u32 off = 1; off < (u32)NB; off <<= 1) {
        u32 add = (tid + off < (u32)NB) ? lh[tid + off] : 0u;
        __syncthreads();
        lh[tid] += add;
        __syncthreads();
    }
    if (lh[tid] >= (u32)K_TOP && (tid == NB - 1 || lh[tid + 1] < (u32)K_TOP)) {
        s_b = (u32)tid; s_cnt = lh[tid];
    }
    __syncthreads();
    const u32 bstar = s_b;
    const u32 cnt_at = s_cnt;
    bool fastok = (s_bad == 0u) && (bstar != 0xFFFFFFFFu) &&
                  (bstar >= (u32)B_SAFE) && (cnt_at <= (u32)CAP);
    const u64* spn = spec + (size_t)n * NSEG * GBUF;
    if (fastok) {
        const u32 span = (u32)NB - bstar;            // <= 76
        const u32 keymin = KEY_BASE + (bstar << 16);
        if (tid <= (int)span) sfxl[tid] = (bstar + (u32)tid < (u32)NB) ? lh[bstar + tid] : 0u;
        if (tid < (int)span) bkc[tid] = 0u;
        __syncthreads();
        // wave-per-segment filter + bucket-grouped placement
        for (int sr = 0; sr < NSEG; sr += 16) {
            int s2 = sr + wid;
            u32 cnt = segc[s2];
            const u64* sp = spn + (size_t)s2 * GBUF;
            for (u32 i = lane; i < cnt; i += 64) {
                u64 e = sp[i];
                u32 bits = (u32)(e >> 32);
                if (bits >= keymin) {
                    u32 t = score_bucket(bits) - bstar;
                    u32 pos = sfxl[t + 1] + atomicAdd(&bkc[t], 1u);
                    if (pos < (u32)CAP) sk[pos] = e;
                }
            }
        }
        __syncthreads();
        // within-bucket rank + direct emit (keys unique -> ranks unique, complete)
        for (u32 p = tid; p < cnt_at; p += 1024) {
            u64 e = sk[p];
            u32 t = score_bucket((u32)(e >> 32)) - bstar;
            u32 r = sfxl[t + 1];
            const u32 qe = sfxl[t];
            for (u32 q = sfxl[t + 1]; q < qe; ++q) r += (sk[q] > e) ? 1u : 0u;
            if (r < (u32)K_TOP)
                emit_one(n, e, (int)r, locations, breg, isz, out);
        }
        return;
    }
    // ---------- SLOW path (gated; full per-image pipeline; r12-proven) ----------
    lh[tid] = 0u;
    if (tid == 0) { s_b = 0xFFFFFFFFu; s_lcnt = 0; s_filled = 0; }
    __syncthreads();
    const float* cls_n = cls + (size_t)n * LC;
    const float* ctr_n = ctr + (size_t)n * L_LOC;
    for (u32 f = tid; f < (u32)LC; f += 1024) {
        float s = sigmoidf_acc(cls_n[f]);
        if (s > THRESH) {
            float scr = s * sigmoidf_acc(ctr_n[f % (u32)L_LOC]);
            atomicAdd(&lh[score_bucket(__float_as_uint(scr))], 1u);
        }
    }
    __syncthreads();
    for (u32 off = 1; off < (u32)NB; off <<= 1) {
        u32 add = (tid + off < (u32)NB) ? lh[tid + off] : 0u;
        __syncthreads();
        lh[tid] += add;
        __syncthreads();
    }
    if (lh[tid] >= (u32)K_TOP && (tid == NB - 1 || lh[tid + 1] < (u32)K_TOP))
        s_b = (u32)tid;
    __syncthreads();
    const u32 total = lh[0];
    const u32 keymin = (s_b != 0xFFFFFFFFu) ? (KEY_BASE + (s_b << 16)) : 0u;
    __syncthreads();
    for (u32 f = tid; f < (u32)LC; f += 1024) {
        float s = sigmoidf_acc(cls_n[f]);
        if (s > THRESH) {
            u32 loc = f % (u32)L_LOC;
            u32 c = f / (u32)L_LOC;
            float scr = s * sigmoidf_acc(ctr_n[loc]);
            u32 bits = __float_as_uint(scr);
            if (bits >= keymin) {
                u32 p = atomicAdd(&s_lcnt, 1u);
                if (p < (u32)CAP)
                    sk[p] = ((u64)bits << 32) | (u32)(~(loc * (u32)C_CLS + c));
            }
        }
    }
    __syncthreads();
    u32 M = s_lcnt > (u32)CAP ? (u32)CAP : s_lcnt;
    u32 cand_slots = total < (u32)K_TOP ? total : (u32)K_TOP;
    if (total < (u32)K_TOP) {                        // fallback fill list
        const u32 need = (u32)K_TOP - total;
        for (u32 basei = 0; basei < (u32)LC; basei += 1024) {
            u32 idx = basei + tid;
            u32 flag = 0;
            if (idx < (u32)LC) {
                u32 loc = idx / (u32)C_CLS;
                u32 c = idx - loc * (u32)C_CLS;
                float x = cls_n[(size_t)c * L_LOC + loc];
                flag = (sigmoidf_acc(x) > THRESH) ? 0u : 1u;
            }
            lh[tid] = flag;
            __syncthreads();
            for (u32 off = 1; off < 1024; off <<= 1) {
                u32 v = (tid >= (int)off) ? lh[tid - off] : 0u;
                __syncthreads();
                lh[tid] += v;
                __syncthreads();
            }
            u32 excl = lh[tid] - flag;
            u32 pos = s_filled + excl;
            if (flag && pos < need) fill[pos] = idx;
            __syncthreads();
            if (tid == 0) s_filled += lh[1023];
            __syncthreads();
            if (s_filled >= need) break;
        }
    }
    bitonic_desc(sk, M, tid, 1024);
    emit_rows(n, sk, cand_slots, fill, locations, breg, isz, out, tid, 1024);
}

extern "C" void kernel_launch(void* const* d_in, const int* in_sizes, int n_in,
                              void* d_out, int out_size, void* d_ws, size_t ws_size,
                              hipStream_t stream) {
    const float* locations = (const float*)d_in[0];
    const float* cls       = (const float*)d_in[1];
    const float* breg      = (const float*)d_in[2];
    const float* ctr       = (const float*)d_in[3];
    const int*   isz       = (const int*)d_in[4];
    float* out = (float*)d_out;

    char* ws = (char*)d_ws;
    u32* bcnt   = (u32*)(ws + WS_BCNT);
    u32* hcnt   = (u32*)(ws + WS_HCNT);
    u64* hpairs = (u64*)(ws + WS_HPAIR);
    u64* spec   = (u64*)(ws + WS_SPEC);

    megaA_kernel<<<dim3(NSEG, N_IMG), 256, 0, stream>>>(cls, ctr, spec, bcnt, hcnt, hpairs);
    finishC_kernel<<<N_IMG, 1024, 0, stream>>>(hpairs, hcnt, spec, bcnt, cls, ctr,
                                               locations, breg, isz, out);
}